// Round 6
// baseline (1102.870 us; speedup 1.0000x reference)
//
#include <hip/hip_runtime.h>

#define NN 200000
#define NE 2000000
#define NG 10000

#define NPB 256                       // nodes per bucket (dst>>8)
#define NBKT 782                      // ceil(NN/NPB)
#define EPB 8192                      // edges per partition block
#define NPBLK 245                     // ceil(NE/EPB)
#define SCAN_N (NBKT * NPBLK)         // 191,590
#define SCAN_PAD 191592               // pad for alignment
#define NSB1 ((SCAN_N + 255) / 256)   // 749

__device__ __forceinline__ void fadd(float* p, float v) {
    unsafeAtomicAdd(p, v);  // HW global_atomic_add_f32
}

// ---------------- node embedding: h = x @ node_w + node_b  [N,14]->[N,32]
__global__ __launch_bounds__(256) void k_node_embed(const float* __restrict__ x,
                                                    const float* __restrict__ w,
                                                    const float* __restrict__ b,
                                                    float* __restrict__ h) {
    __shared__ float sw[14 * 32];
    __shared__ float sb[32];
    for (int i = threadIdx.x; i < 14 * 32; i += 256) sw[i] = w[i];
    if (threadIdx.x < 32) sb[threadIdx.x] = b[threadIdx.x];
    __syncthreads();
    int n = blockIdx.x * 256 + threadIdx.x;
    if (n >= NN) return;
    float xi[14];
#pragma unroll
    for (int k = 0; k < 14; ++k) xi[k] = x[n * 14 + k];
#pragma unroll
    for (int c = 0; c < 32; c += 4) {
        float4 acc = make_float4(sb[c], sb[c + 1], sb[c + 2], sb[c + 3]);
#pragma unroll
        for (int k = 0; k < 14; ++k) {
            float xv = xi[k];
            acc.x += xv * sw[k * 32 + c + 0];
            acc.y += xv * sw[k * 32 + c + 1];
            acc.z += xv * sw[k * 32 + c + 2];
            acc.w += xv * sw[k * 32 + c + 3];
        }
        *(float4*)(h + n * 32 + c) = acc;
    }
}

// ================= bucket partition (once per launch) =================
// pass 1: per-(bucket, block) histogram, bucket-major layout for the scan
__global__ __launch_bounds__(256) void k_hist(const int* __restrict__ ei,
                                              int* __restrict__ counts) {
    __shared__ int hist[NBKT];
    for (int i = threadIdx.x; i < NBKT; i += 256) hist[i] = 0;
    __syncthreads();
    int base = blockIdx.x * EPB;
#pragma unroll
    for (int k = 0; k < EPB / 256; ++k) {
        int e = base + k * 256 + threadIdx.x;
        if (e < NE) atomicAdd(&hist[ei[NE + e] >> 8], 1);
    }
    __syncthreads();
    for (int b = threadIdx.x; b < NBKT; b += 256)
        counts[b * NPBLK + blockIdx.x] = hist[b];
}

// pass 2: exclusive scan over counts (in-place) — 3 kernels
__global__ __launch_bounds__(256) void k_scanA(int* __restrict__ data,
                                               int* __restrict__ part) {
    __shared__ int s[256];
    int tid = threadIdx.x;
    int i = blockIdx.x * 256 + tid;
    int v = (i < SCAN_N) ? data[i] : 0;
    s[tid] = v;
    __syncthreads();
    for (int off = 1; off < 256; off <<= 1) {
        int t = (tid >= off) ? s[tid - off] : 0;
        __syncthreads();
        s[tid] += t;
        __syncthreads();
    }
    if (i < SCAN_N) data[i] = s[tid] - v;
    if (tid == 255) part[blockIdx.x] = s[255];
}

__global__ __launch_bounds__(1024) void k_scanB(int* __restrict__ part) {
    __shared__ int s[1024];
    int tid = threadIdx.x;
    int v = (tid < NSB1) ? part[tid] : 0;
    s[tid] = v;
    __syncthreads();
    for (int off = 1; off < 1024; off <<= 1) {
        int t = (tid >= off) ? s[tid - off] : 0;
        __syncthreads();
        s[tid] += t;
        __syncthreads();
    }
    if (tid < NSB1) part[tid] = s[tid] - v;  // exclusive
}

__global__ __launch_bounds__(256) void k_scanC(int* __restrict__ data,
                                               const int* __restrict__ part) {
    int i = blockIdx.x * 256 + threadIdx.x;
    if (i < SCAN_N) data[i] += part[blockIdx.x];
}

// pass 3: scatter packed records; each (block,bucket) chunk is contiguous
__global__ __launch_bounds__(256) void k_part_scatter(const int* __restrict__ ei,
                                                      const float* __restrict__ ea,
                                                      const int* __restrict__ counts,
                                                      float4* __restrict__ recs) {
    __shared__ int sbase[NBKT];
    __shared__ int scnt[NBKT];
    for (int i = threadIdx.x; i < NBKT; i += 256) {
        sbase[i] = counts[i * NPBLK + blockIdx.x];
        scnt[i] = 0;
    }
    __syncthreads();
    int base = blockIdx.x * EPB;
#pragma unroll
    for (int k = 0; k < EPB / 256; ++k) {
        int e = base + k * 256 + threadIdx.x;
        if (e >= NE) continue;
        int dst = ei[NE + e];
        int bkt = dst >> 8;
        int nl = dst & 255;
        int r = atomicAdd(&scnt[bkt], 1);
        int src = ei[e];
        recs[sbase[bkt] + r] = make_float4(__int_as_float(src | (nl << 24)),
                                           ea[e * 3 + 0], ea[e * 3 + 1], ea[e * 3 + 2]);
    }
}

// ---------------- bucket aggregation: LDS accumulator, no global atomics
__global__ __launch_bounds__(512) void k_bucket_agg(const int* __restrict__ counts,
                                                    const float4* __restrict__ recs,
                                                    const float* __restrict__ ew,
                                                    const float* __restrict__ eb,
                                                    const float* __restrict__ h,
                                                    float* __restrict__ agg) {
    __shared__ float acc[NPB * 33];  // stride 33 to spread LDS banks
    __shared__ float sw[96];
    __shared__ float sb[32];
    int tid = threadIdx.x;
    if (tid < 96) sw[tid] = ew[tid];
    if (tid < 32) sb[tid] = eb[tid];
    for (int i = tid; i < NPB * 33; i += 512) acc[i] = 0.f;
    __syncthreads();

    int b = blockIdx.x;
    int boff = counts[b * NPBLK];
    int bend = (b == NBKT - 1) ? NE : counts[(b + 1) * NPBLK];
    int c = (tid & 7) * 4;
    float w0[4], w1[4], w2[4], bb[4];
#pragma unroll
    for (int j = 0; j < 4; ++j) {
        w0[j] = sw[c + j];
        w1[j] = sw[32 + c + j];
        w2[j] = sw[64 + c + j];
        bb[j] = sb[c + j];
    }
    for (int i = boff + (tid >> 3); i < bend; i += 64) {
        float4 r = recs[i];
        int w = __float_as_int(r.x);
        int src = w & 0x00FFFFFF;
        int nl = (w >> 24) & 0xFF;
        float4 hs = *(const float4*)(h + (size_t)src * 32 + c);
        float m0 = fmaxf(hs.x + bb[0] + r.y * w0[0] + r.z * w1[0] + r.w * w2[0], 0.f);
        float m1 = fmaxf(hs.y + bb[1] + r.y * w0[1] + r.z * w1[1] + r.w * w2[1], 0.f);
        float m2 = fmaxf(hs.z + bb[2] + r.y * w0[2] + r.z * w1[2] + r.w * w2[2], 0.f);
        float m3 = fmaxf(hs.w + bb[3] + r.y * w0[3] + r.z * w1[3] + r.w * w2[3], 0.f);
        float* a = acc + nl * 33 + c;
        atomicAdd(a + 0, m0);
        atomicAdd(a + 1, m1);
        atomicAdd(a + 2, m2);
        atomicAdd(a + 3, m3);
    }
    __syncthreads();

    int n0 = b * NPB;
    for (int idx = tid; idx < NPB * 8; idx += 512) {
        int nl = idx >> 3;
        int cc = (idx & 7) * 4;
        int n = n0 + nl;
        if (n < NN) {
            const float* a = acc + nl * 33 + cc;
            *(float4*)(agg + (size_t)n * 32 + cc) = make_float4(a[0], a[1], a[2], a[3]);
        }
    }
}

// ---------------- fallback atomic scatter (only if ws too small)
__global__ __launch_bounds__(256) void k_edge_scatter(const int* __restrict__ ei,
                                                      const float* __restrict__ ea,
                                                      const float* __restrict__ ew,
                                                      const float* __restrict__ eb,
                                                      const float* __restrict__ h,
                                                      float* __restrict__ agg) {
    __shared__ float sw[96];
    __shared__ float sb[32];
    if (threadIdx.x < 96) sw[threadIdx.x] = ew[threadIdx.x];
    if (threadIdx.x < 32) sb[threadIdx.x] = eb[threadIdx.x];
    __syncthreads();
    int t = blockIdx.x * 256 + threadIdx.x;
    int edge = t >> 3;
    if (edge >= NE) return;
    int c = (t & 7) * 4;
    int src = ei[edge];
    int dst = ei[NE + edge];
    float a0 = ea[edge * 3 + 0];
    float a1 = ea[edge * 3 + 1];
    float a2 = ea[edge * 3 + 2];
    float4 hs = *(const float4*)(h + src * 32 + c);
    float m0 = hs.x + sb[c + 0] + a0 * sw[c + 0] + a1 * sw[32 + c + 0] + a2 * sw[64 + c + 0];
    float m1 = hs.y + sb[c + 1] + a0 * sw[c + 1] + a1 * sw[32 + c + 1] + a2 * sw[64 + c + 1];
    float m2 = hs.z + sb[c + 2] + a0 * sw[c + 2] + a1 * sw[32 + c + 2] + a2 * sw[64 + c + 2];
    float m3 = hs.w + sb[c + 3] + a0 * sw[c + 3] + a1 * sw[32 + c + 3] + a2 * sw[64 + c + 3];
    float* o = agg + (size_t)dst * 32 + c;
    fadd(o + 0, fmaxf(m0, 0.f));
    fadd(o + 1, fmaxf(m1, 0.f));
    fadd(o + 2, fmaxf(m2, 0.f));
    fadd(o + 3, fmaxf(m3, 0.f));
}

// ---------------- node MLP: z = relu((h+agg)@w1+b1)@w2+b2 ; in-place over agg
__global__ __launch_bounds__(256) void k_mlp(const float* __restrict__ h,
                                             float* zio,
                                             const float* __restrict__ w1,
                                             const float* __restrict__ b1,
                                             const float* __restrict__ w2,
                                             const float* __restrict__ b2) {
    __shared__ float sw1[75 * 32];  // transposed: [j][k]
    __shared__ float sw2[75 * 32];  // [j][k]
    __shared__ float sb1[75];
    __shared__ float sb2[32];
    for (int i = threadIdx.x; i < 2400; i += 256) {
        int k = i / 75, j = i % 75;
        sw1[j * 32 + k] = w1[i];
        sw2[i] = w2[i];
    }
    if (threadIdx.x < 75) sb1[threadIdx.x] = b1[threadIdx.x];
    if (threadIdx.x < 32) sb2[threadIdx.x] = b2[threadIdx.x];
    __syncthreads();
    int n = blockIdx.x * 256 + threadIdx.x;
    if (n >= NN) return;
    float z0[32], acc[32];
#pragma unroll
    for (int c = 0; c < 32; c += 4) {
        float4 hv = *(const float4*)(h + (size_t)n * 32 + c);
        float4 av = *(const float4*)(zio + (size_t)n * 32 + c);
        z0[c + 0] = hv.x + av.x;
        z0[c + 1] = hv.y + av.y;
        z0[c + 2] = hv.z + av.z;
        z0[c + 3] = hv.w + av.w;
    }
#pragma unroll
    for (int k = 0; k < 32; ++k) acc[k] = sb2[k];
    for (int j = 0; j < 75; ++j) {
        float tj = sb1[j];
#pragma unroll
        for (int k = 0; k < 32; ++k) tj += z0[k] * sw1[j * 32 + k];
        tj = fmaxf(tj, 0.f);
#pragma unroll
        for (int k = 0; k < 32; ++k) acc[k] += tj * sw2[j * 32 + k];
    }
#pragma unroll
    for (int c = 0; c < 32; c += 4) {
        *(float4*)(zio + (size_t)n * 32 + c) = make_float4(acc[c], acc[c + 1], acc[c + 2], acc[c + 3]);
    }
}

// ---------------- BN stats
__global__ __launch_bounds__(256) void k_bn_stats(const float* __restrict__ z,
                                                  float* __restrict__ stats) {
    int tid = threadIdx.x;
    int gid = blockIdx.x * 256 + tid;
    float4 s = make_float4(0, 0, 0, 0), q = make_float4(0, 0, 0, 0);
    const int total = NN * 8;
    int stride = gridDim.x * 256;
    for (int i = gid; i < total; i += stride) {
        float4 v = *(const float4*)(z + (size_t)i * 4);
        s.x += v.x; s.y += v.y; s.z += v.z; s.w += v.w;
        q.x += v.x * v.x; q.y += v.y * v.y; q.z += v.z * v.z; q.w += v.w * v.w;
    }
#pragma unroll
    for (int off = 8; off < 64; off <<= 1) {
        s.x += __shfl_xor(s.x, off); s.y += __shfl_xor(s.y, off);
        s.z += __shfl_xor(s.z, off); s.w += __shfl_xor(s.w, off);
        q.x += __shfl_xor(q.x, off); q.y += __shfl_xor(q.y, off);
        q.z += __shfl_xor(q.z, off); q.w += __shfl_xor(q.w, off);
    }
    __shared__ float ls[4][64];
    int wave = tid >> 6, lane = tid & 63;
    if (lane < 8) {
        int cb = lane * 4;
        ls[wave][cb + 0] = s.x; ls[wave][cb + 1] = s.y;
        ls[wave][cb + 2] = s.z; ls[wave][cb + 3] = s.w;
        ls[wave][32 + cb + 0] = q.x; ls[wave][32 + cb + 1] = q.y;
        ls[wave][32 + cb + 2] = q.z; ls[wave][32 + cb + 3] = q.w;
    }
    __syncthreads();
    if (tid < 64) {
        float v = ls[0][tid] + ls[1][tid] + ls[2][tid] + ls[3][tid];
        fadd(&stats[tid], v);
    }
}

__global__ void k_bn_finalize(const float* __restrict__ stats,
                              const float* __restrict__ g,
                              const float* __restrict__ b,
                              float* __restrict__ deriv) {
    int c = threadIdx.x;
    if (c >= 32) return;
    float mu = stats[c] * (1.0f / NN);
    float var = stats[32 + c] * (1.0f / NN) - mu * mu;
    float sc = g[c] * rsqrtf(var + 1e-5f);
    deriv[c] = sc;
    deriv[32 + c] = b[c] - mu * sc;
}

__global__ __launch_bounds__(256) void k_norm_relu(const float* __restrict__ z,
                                                   const float* __restrict__ deriv,
                                                   float* __restrict__ h) {
    __shared__ float sc[32], sh[32];
    if (threadIdx.x < 32) {
        sc[threadIdx.x] = deriv[threadIdx.x];
        sh[threadIdx.x] = deriv[32 + threadIdx.x];
    }
    __syncthreads();
    int i = blockIdx.x * 256 + threadIdx.x;
    if (i >= NN * 8) return;
    int c = (i & 7) * 4;
    float4 v = *(const float4*)(z + (size_t)i * 4);
    float4 o;
    o.x = fmaxf(v.x * sc[c + 0] + sh[c + 0], 0.f);
    o.y = fmaxf(v.y * sc[c + 1] + sh[c + 1], 0.f);
    o.z = fmaxf(v.z * sc[c + 2] + sh[c + 2], 0.f);
    o.w = fmaxf(v.w * sc[c + 3] + sh[c + 3], 0.f);
    *(float4*)(h + (size_t)i * 4) = o;
}

// ---------------- pool: batch is SORTED — accumulate runs, flush per boundary
__global__ __launch_bounds__(256) void k_pool(const float* __restrict__ h,
                                              const int* __restrict__ batch,
                                              float* __restrict__ gsum,
                                              float* __restrict__ gcnt) {
    int gid = blockIdx.x * 256 + threadIdx.x;
    int nb = (gid >> 3) * 8;  // 8 consecutive nodes per thread-octet
    if (nb >= NN) return;
    int c = (gid & 7) * 4;
    bool lead = (gid & 7) == 0;
    float4 acc = make_float4(0.f, 0.f, 0.f, 0.f);
    float cnt = 0.f;
    int cur = batch[nb];
#pragma unroll
    for (int k = 0; k < 8; ++k) {
        int n = nb + k;
        if (n >= NN) break;
        int bg = batch[n];
        if (bg != cur) {
            float* o = gsum + (size_t)cur * 32 + c;
            fadd(o + 0, acc.x); fadd(o + 1, acc.y);
            fadd(o + 2, acc.z); fadd(o + 3, acc.w);
            if (lead) fadd(&gcnt[cur], cnt);
            acc = make_float4(0.f, 0.f, 0.f, 0.f);
            cnt = 0.f;
            cur = bg;
        }
        float4 v = *(const float4*)(h + (size_t)n * 32 + c);
        acc.x += v.x; acc.y += v.y; acc.z += v.z; acc.w += v.w;
        cnt += 1.f;
    }
    float* o = gsum + (size_t)cur * 32 + c;
    fadd(o + 0, acc.x); fadd(o + 1, acc.y);
    fadd(o + 2, acc.z); fadd(o + 3, acc.w);
    if (lead) fadd(&gcnt[cur], cnt);
}

__global__ __launch_bounds__(256) void k_head(const float* __restrict__ gsum,
                                              const float* __restrict__ gcnt,
                                              const float* __restrict__ l1w,
                                              const float* __restrict__ l1b,
                                              const float* __restrict__ l2w,
                                              const float* __restrict__ l2b,
                                              float* __restrict__ out) {
    __shared__ float s1[32 * 16], sb1[16], s2[16 * 2], sb2[2];
    for (int i = threadIdx.x; i < 512; i += 256) s1[i] = l1w[i];
    if (threadIdx.x < 16) sb1[threadIdx.x] = l1b[threadIdx.x];
    if (threadIdx.x < 32) s2[threadIdx.x] = l2w[threadIdx.x];
    if (threadIdx.x < 2) sb2[threadIdx.x] = l2b[threadIdx.x];
    __syncthreads();
    int gi = blockIdx.x * 256 + threadIdx.x;
    if (gi >= NG) return;
    float inv = 1.0f / fmaxf(gcnt[gi], 1.0f);
    float gm[32];
#pragma unroll
    for (int c = 0; c < 32; c += 4) {
        float4 v = *(const float4*)(gsum + (size_t)gi * 32 + c);
        gm[c + 0] = v.x * inv;
        gm[c + 1] = v.y * inv;
        gm[c + 2] = v.z * inv;
        gm[c + 3] = v.w * inv;
    }
    float a[16];
#pragma unroll
    for (int j = 0; j < 16; ++j) {
        float t = sb1[j];
#pragma unroll
        for (int c = 0; c < 32; ++c) t += gm[c] * s1[c * 16 + j];
        a[j] = fmaxf(t, 0.f);
    }
    float o0 = sb2[0], o1 = sb2[1];
#pragma unroll
    for (int j = 0; j < 16; ++j) {
        o0 += a[j] * s2[j * 2 + 0];
        o1 += a[j] * s2[j * 2 + 1];
    }
    out[gi * 2 + 0] = o0;
    out[gi * 2 + 1] = o1;
}

extern "C" void kernel_launch(void* const* d_in, const int* in_sizes, int n_in,
                              void* d_out, int out_size, void* d_ws, size_t ws_size,
                              hipStream_t stream) {
    const float* x = (const float*)d_in[0];
    const int* ei = (const int*)d_in[1];
    const float* ea = (const float*)d_in[2];
    const int* batch = (const int*)d_in[3];
    const float* node_w = (const float*)d_in[4];
    const float* node_b = (const float*)d_in[5];
    const float* edge_w = (const float*)d_in[6];
    const float* edge_b = (const float*)d_in[7];
    const float* w1 = (const float*)d_in[8];
    const float* b1 = (const float*)d_in[9];
    const float* w2 = (const float*)d_in[10];
    const float* b2 = (const float*)d_in[11];
    const float* bng = (const float*)d_in[12];
    const float* bnb = (const float*)d_in[13];
    const float* l1w = (const float*)d_in[14];
    const float* l1b = (const float*)d_in[15];
    const float* l2w = (const float*)d_in[16];
    const float* l2b = (const float*)d_in[17];
    float* out = (float*)d_out;

    // workspace layout (units: float/4B); recs kept 16B-aligned
    float* h = (float*)d_ws;                       // NN*32 = 6,400,000
    float* zb = h + (size_t)NN * 32;               // NN*32
    float* gsum = zb + (size_t)NN * 32;            // NG*32 = 320,000
    float* gcnt = gsum + (size_t)NG * 32;          // NG
    float* stats = gcnt + NG;                      // 64
    float* deriv = stats + 64;                     // 64
    int* counts = (int*)(deriv + 64);              // SCAN_PAD (191,592)
    int* part = counts + SCAN_PAD;                 // 1024
    float4* recs = (float4*)(part + 1024);         // NE float4s

    size_t need_f = (size_t)NN * 64 + (size_t)NG * 33 + 128 + SCAN_PAD + 1024 + (size_t)NE * 4;
    bool use_bkt = ws_size >= need_f * 4;

    k_node_embed<<<(NN + 255) / 256, 256, 0, stream>>>(x, node_w, node_b, h);

    if (use_bkt) {
        k_hist<<<NPBLK, 256, 0, stream>>>(ei, counts);
        k_scanA<<<NSB1, 256, 0, stream>>>(counts, part);
        k_scanB<<<1, 1024, 0, stream>>>(part);
        k_scanC<<<NSB1, 256, 0, stream>>>(counts, part);
        k_part_scatter<<<NPBLK, 256, 0, stream>>>(ei, ea, counts, recs);
    }

    for (int l = 0; l < 2; ++l) {
        hipMemsetAsync(stats, 0, 64 * sizeof(float), stream);
        if (use_bkt) {
            k_bucket_agg<<<NBKT, 512, 0, stream>>>(counts, recs, edge_w, edge_b, h, zb);
        } else {
            hipMemsetAsync(zb, 0, (size_t)NN * 32 * sizeof(float), stream);
            k_edge_scatter<<<(NE * 8) / 256, 256, 0, stream>>>(ei, ea, edge_w, edge_b, h, zb);
        }
        k_mlp<<<(NN + 255) / 256, 256, 0, stream>>>(h, zb, w1 + l * 2400, b1 + l * 75,
                                                    w2 + l * 2400, b2 + l * 32);
        k_bn_stats<<<1024, 256, 0, stream>>>(zb, stats);
        k_bn_finalize<<<1, 64, 0, stream>>>(stats, bng + l * 32, bnb + l * 32, deriv);
        k_norm_relu<<<(NN * 8 + 255) / 256, 256, 0, stream>>>(zb, deriv, h);
    }

    hipMemsetAsync(gsum, 0, (size_t)(NG * 33) * sizeof(float), stream);
    k_pool<<<(NN + 255) / 256, 256, 0, stream>>>(h, batch, gsum, gcnt);
    k_head<<<(NG + 255) / 256, 256, 0, stream>>>(gsum, gcnt, l1w, l1b, l2w, l2b, out);
}

// Round 7
// 378.602 us; speedup vs baseline: 2.9130x; 2.9130x over previous
//
#include <hip/hip_runtime.h>
#include <hip/hip_fp16.h>

#define NN 200000
#define NE 2000000
#define NG 10000

#define NPB 256                       // nodes per bucket (dst>>8)
#define NBKT 782                      // ceil(NN/NPB)
#define EPB 8192                      // edges per partition block
#define NPBLK 245                     // ceil(NE/EPB)
#define SCAN_N (NBKT * NPBLK)         // 191,590
#define SCAN_PAD 191592
#define NSB1 ((SCAN_N + 255) / 256)   // 749

__device__ __forceinline__ void fadd(float* p, float v) {
    unsafeAtomicAdd(p, v);  // HW global_atomic_add_f32
}

// ---------------- node embedding: h = x @ node_w + node_b  [N,14]->[N,32]
__global__ __launch_bounds__(256) void k_node_embed(const float* __restrict__ x,
                                                    const float* __restrict__ w,
                                                    const float* __restrict__ b,
                                                    float* __restrict__ h) {
    __shared__ float sw[14 * 32];
    __shared__ float sb[32];
    for (int i = threadIdx.x; i < 14 * 32; i += 256) sw[i] = w[i];
    if (threadIdx.x < 32) sb[threadIdx.x] = b[threadIdx.x];
    __syncthreads();
    int n = blockIdx.x * 256 + threadIdx.x;
    if (n >= NN) return;
    float xi[14];
#pragma unroll
    for (int k = 0; k < 14; ++k) xi[k] = x[n * 14 + k];
#pragma unroll
    for (int c = 0; c < 32; c += 4) {
        float4 acc = make_float4(sb[c], sb[c + 1], sb[c + 2], sb[c + 3]);
#pragma unroll
        for (int k = 0; k < 14; ++k) {
            float xv = xi[k];
            acc.x += xv * sw[k * 32 + c + 0];
            acc.y += xv * sw[k * 32 + c + 1];
            acc.z += xv * sw[k * 32 + c + 2];
            acc.w += xv * sw[k * 32 + c + 3];
        }
        *(float4*)(h + n * 32 + c) = acc;
    }
}

// ================= bucket partition + per-bucket sort (once per launch) =========
// pass 1: per-(bucket, block) histogram, bucket-major for the scan
__global__ __launch_bounds__(256) void k_hist(const int* __restrict__ ei,
                                              int* __restrict__ counts) {
    __shared__ int hist[NBKT];
    for (int i = threadIdx.x; i < NBKT; i += 256) hist[i] = 0;
    __syncthreads();
    int base = blockIdx.x * EPB;
#pragma unroll
    for (int k = 0; k < EPB / 256; ++k) {
        int e = base + k * 256 + threadIdx.x;
        if (e < NE) atomicAdd(&hist[ei[NE + e] >> 8], 1);
    }
    __syncthreads();
    for (int b = threadIdx.x; b < NBKT; b += 256)
        counts[b * NPBLK + blockIdx.x] = hist[b];
}

__global__ __launch_bounds__(256) void k_scanA(int* __restrict__ data,
                                               int* __restrict__ part) {
    __shared__ int s[256];
    int tid = threadIdx.x;
    int i = blockIdx.x * 256 + tid;
    int v = (i < SCAN_N) ? data[i] : 0;
    s[tid] = v;
    __syncthreads();
    for (int off = 1; off < 256; off <<= 1) {
        int t = (tid >= off) ? s[tid - off] : 0;
        __syncthreads();
        s[tid] += t;
        __syncthreads();
    }
    if (i < SCAN_N) data[i] = s[tid] - v;
    if (tid == 255) part[blockIdx.x] = s[255];
}

__global__ __launch_bounds__(1024) void k_scanB(int* __restrict__ part) {
    __shared__ int s[1024];
    int tid = threadIdx.x;
    int v = (tid < NSB1) ? part[tid] : 0;
    s[tid] = v;
    __syncthreads();
    for (int off = 1; off < 1024; off <<= 1) {
        int t = (tid >= off) ? s[tid - off] : 0;
        __syncthreads();
        s[tid] += t;
        __syncthreads();
    }
    if (tid < NSB1) part[tid] = s[tid] - v;
}

__global__ __launch_bounds__(256) void k_scanC(int* __restrict__ data,
                                               const int* __restrict__ part) {
    int i = blockIdx.x * 256 + threadIdx.x;
    if (i < SCAN_N) data[i] += part[blockIdx.x];
}

// pass 3: scatter packed 12B records into bucket-chunk order (writes block-local chunks)
// rec = { src | nl<<24, half2(ea0,ea1), half(ea2) }
__global__ __launch_bounds__(256) void k_part_scatter(const int* __restrict__ ei,
                                                      const float* __restrict__ ea,
                                                      const int* __restrict__ counts,
                                                      uint3* __restrict__ tmp) {
    __shared__ int sbase[NBKT];
    __shared__ int scnt[NBKT];
    for (int i = threadIdx.x; i < NBKT; i += 256) {
        sbase[i] = counts[i * NPBLK + blockIdx.x];
        scnt[i] = 0;
    }
    __syncthreads();
    int base = blockIdx.x * EPB;
#pragma unroll
    for (int k = 0; k < EPB / 256; ++k) {
        int e = base + k * 256 + threadIdx.x;
        if (e >= NE) continue;
        int dst = ei[NE + e];
        int bkt = dst >> 8;
        int nl = dst & 255;
        int r = atomicAdd(&scnt[bkt], 1);
        int src = ei[e];
        __half2 p01 = __floats2half2_rn(ea[e * 3 + 0], ea[e * 3 + 1]);
        __half p2 = __float2half_rn(ea[e * 3 + 2]);
        uint3 rec;
        rec.x = (uint)(src | (nl << 24));
        rec.y = *reinterpret_cast<const uint*>(&p01);
        rec.z = (uint)__half_as_ushort(p2);
        tmp[sbase[bkt] + r] = rec;
    }
}

// pass 4: per-bucket LDS counting sort -> exact node-sorted recs2 + row_off
__global__ __launch_bounds__(256) void k_bucket_sort(const int* __restrict__ counts,
                                                     const uint3* __restrict__ tmp,
                                                     uint3* __restrict__ recs2,
                                                     int* __restrict__ row_off) {
    __shared__ int cnt[NPB];
    __shared__ int s[NPB];
    int tid = threadIdx.x;
    int b = blockIdx.x;
    int boff = counts[b * NPBLK];
    int bend = (b == NBKT - 1) ? NE : counts[(b + 1) * NPBLK];
    cnt[tid] = 0;
    __syncthreads();
    for (int i = boff + tid; i < bend; i += 256)
        atomicAdd(&cnt[(tmp[i].x >> 24) & 255], 1);
    __syncthreads();
    int v = cnt[tid];
    s[tid] = v;
    __syncthreads();
    for (int off = 1; off < 256; off <<= 1) {
        int t = (tid >= off) ? s[tid - off] : 0;
        __syncthreads();
        s[tid] += t;
        __syncthreads();
    }
    int excl = s[tid] - v;
    int n = b * NPB + tid;
    if (n < NN) row_off[n] = boff + excl;
    if (b == NBKT - 1 && tid == 0) row_off[NN] = NE;
    cnt[tid] = excl;  // becomes fill counter
    __syncthreads();
    for (int i = boff + tid; i < bend; i += 256) {
        uint3 r = tmp[i];
        int nl = (r.x >> 24) & 255;
        int p = atomicAdd(&cnt[nl], 1);
        recs2[boff + p] = r;
    }
}

// ---------------- exact-CSR gather aggregation: 8 thr/node, unroll x2
__global__ __launch_bounds__(256) void k_aggregate(const int* __restrict__ row_off,
                                                   const uint3* __restrict__ recs,
                                                   const float* __restrict__ ew,
                                                   const float* __restrict__ eb,
                                                   const float* __restrict__ h,
                                                   float* __restrict__ agg) {
    __shared__ float sw[96];
    __shared__ float sb[32];
    if (threadIdx.x < 96) sw[threadIdx.x] = ew[threadIdx.x];
    if (threadIdx.x < 32) sb[threadIdx.x] = eb[threadIdx.x];
    __syncthreads();
    int t = blockIdx.x * 256 + threadIdx.x;
    int n = t >> 3;
    if (n >= NN) return;
    int c = (t & 7) * 4;
    float w0[4], w1[4], w2[4], bb[4];
#pragma unroll
    for (int j = 0; j < 4; ++j) {
        w0[j] = sw[c + j];
        w1[j] = sw[32 + c + j];
        w2[j] = sw[64 + c + j];
        bb[j] = sb[c + j];
    }
    float4 acc = make_float4(0.f, 0.f, 0.f, 0.f);
    int s0 = row_off[n], s1 = row_off[n + 1];
    int i = s0;
    for (; i + 2 <= s1; i += 2) {
        uint3 r0 = recs[i];
        uint3 r1 = recs[i + 1];
        int src0 = r0.x & 0x00FFFFFF;
        int src1 = r1.x & 0x00FFFFFF;
        float4 h0 = *(const float4*)(h + (size_t)src0 * 32 + c);
        float4 h1 = *(const float4*)(h + (size_t)src1 * 32 + c);
        float2 e01a = __half22float2(*reinterpret_cast<const __half2*>(&r0.y));
        float e2a = __half2float(__ushort_as_half((unsigned short)(r0.z & 0xFFFF)));
        float2 e01b = __half22float2(*reinterpret_cast<const __half2*>(&r1.y));
        float e2b = __half2float(__ushort_as_half((unsigned short)(r1.z & 0xFFFF)));
#pragma unroll
        for (int j = 0; j < 4; ++j) {
            float ha = (&h0.x)[j];
            float hb = (&h1.x)[j];
            float ma = ha + bb[j] + e01a.x * w0[j] + e01a.y * w1[j] + e2a * w2[j];
            float mb = hb + bb[j] + e01b.x * w0[j] + e01b.y * w1[j] + e2b * w2[j];
            (&acc.x)[j] += fmaxf(ma, 0.f) + fmaxf(mb, 0.f);
        }
    }
    if (i < s1) {
        uint3 r0 = recs[i];
        int src0 = r0.x & 0x00FFFFFF;
        float4 h0 = *(const float4*)(h + (size_t)src0 * 32 + c);
        float2 e01a = __half22float2(*reinterpret_cast<const __half2*>(&r0.y));
        float e2a = __half2float(__ushort_as_half((unsigned short)(r0.z & 0xFFFF)));
#pragma unroll
        for (int j = 0; j < 4; ++j) {
            float ha = (&h0.x)[j];
            float ma = ha + bb[j] + e01a.x * w0[j] + e01a.y * w1[j] + e2a * w2[j];
            (&acc.x)[j] += fmaxf(ma, 0.f);
        }
    }
    *(float4*)(agg + (size_t)n * 32 + c) = acc;
}

// ---------------- fallback atomic scatter (only if ws too small)
__global__ __launch_bounds__(256) void k_edge_scatter(const int* __restrict__ ei,
                                                      const float* __restrict__ ea,
                                                      const float* __restrict__ ew,
                                                      const float* __restrict__ eb,
                                                      const float* __restrict__ h,
                                                      float* __restrict__ agg) {
    __shared__ float sw[96];
    __shared__ float sb[32];
    if (threadIdx.x < 96) sw[threadIdx.x] = ew[threadIdx.x];
    if (threadIdx.x < 32) sb[threadIdx.x] = eb[threadIdx.x];
    __syncthreads();
    int t = blockIdx.x * 256 + threadIdx.x;
    int edge = t >> 3;
    if (edge >= NE) return;
    int c = (t & 7) * 4;
    int src = ei[edge];
    int dst = ei[NE + edge];
    float a0 = ea[edge * 3 + 0];
    float a1 = ea[edge * 3 + 1];
    float a2 = ea[edge * 3 + 2];
    float4 hs = *(const float4*)(h + src * 32 + c);
    float m0 = hs.x + sb[c + 0] + a0 * sw[c + 0] + a1 * sw[32 + c + 0] + a2 * sw[64 + c + 0];
    float m1 = hs.y + sb[c + 1] + a0 * sw[c + 1] + a1 * sw[32 + c + 1] + a2 * sw[64 + c + 1];
    float m2 = hs.z + sb[c + 2] + a0 * sw[c + 2] + a1 * sw[32 + c + 2] + a2 * sw[64 + c + 2];
    float m3 = hs.w + sb[c + 3] + a0 * sw[c + 3] + a1 * sw[32 + c + 3] + a2 * sw[64 + c + 3];
    float* o = agg + (size_t)dst * 32 + c;
    fadd(o + 0, fmaxf(m0, 0.f));
    fadd(o + 1, fmaxf(m1, 0.f));
    fadd(o + 2, fmaxf(m2, 0.f));
    fadd(o + 3, fmaxf(m3, 0.f));
}

// ---------------- node MLP + fused BN stats: z = relu((h+agg)@w1+b1)@w2+b2
__global__ __launch_bounds__(256) void k_mlp_stats(const float* __restrict__ h,
                                                   float* zio,
                                                   const float* __restrict__ w1,
                                                   const float* __restrict__ b1,
                                                   const float* __restrict__ w2,
                                                   const float* __restrict__ b2,
                                                   float* __restrict__ stats) {
    __shared__ float sw1[75 * 32];  // transposed [j][k]
    __shared__ float sw2[75 * 32];  // [j][k]
    __shared__ float sb1[75];
    __shared__ float sb2[32];
    __shared__ float ls[4][64];
    int tid = threadIdx.x;
    for (int i = tid; i < 2400; i += 256) {
        int k = i / 75, j = i % 75;
        sw1[j * 32 + k] = w1[i];
        sw2[i] = w2[i];
    }
    if (tid < 75) sb1[tid] = b1[tid];
    if (tid < 32) sb2[tid] = b2[tid];
    __syncthreads();
    int n = blockIdx.x * 256 + tid;
    bool valid = n < NN;
    float z0[32], acc[32];
    if (valid) {
#pragma unroll
        for (int c = 0; c < 32; c += 4) {
            float4 hv = *(const float4*)(h + (size_t)n * 32 + c);
            float4 av = *(const float4*)(zio + (size_t)n * 32 + c);
            z0[c + 0] = hv.x + av.x;
            z0[c + 1] = hv.y + av.y;
            z0[c + 2] = hv.z + av.z;
            z0[c + 3] = hv.w + av.w;
        }
#pragma unroll
        for (int k = 0; k < 32; ++k) acc[k] = sb2[k];
        for (int j = 0; j < 75; ++j) {
            float tj = sb1[j];
#pragma unroll
            for (int k = 0; k < 32; ++k) tj += z0[k] * sw1[j * 32 + k];
            tj = fmaxf(tj, 0.f);
#pragma unroll
            for (int k = 0; k < 32; ++k) acc[k] += tj * sw2[j * 32 + k];
        }
#pragma unroll
        for (int c = 0; c < 32; c += 4)
            *(float4*)(zio + (size_t)n * 32 + c) = make_float4(acc[c], acc[c + 1], acc[c + 2], acc[c + 3]);
    } else {
#pragma unroll
        for (int k = 0; k < 32; ++k) acc[k] = 0.f;
    }
    // fused BN statistics: butterfly over 64 lanes, per channel
    int wave = tid >> 6, lane = tid & 63;
#pragma unroll
    for (int k = 0; k < 32; ++k) {
        float sv = valid ? acc[k] : 0.f;
        float qv = sv * sv;
#pragma unroll
        for (int off = 1; off < 64; off <<= 1) {
            sv += __shfl_xor(sv, off);
            qv += __shfl_xor(qv, off);
        }
        if (lane == 0) {
            ls[wave][k] = sv;
            ls[wave][32 + k] = qv;
        }
    }
    __syncthreads();
    if (tid < 64)
        fadd(&stats[tid], ls[0][tid] + ls[1][tid] + ls[2][tid] + ls[3][tid]);
}

// ---------------- normalize + relu (fused finalize): h = relu(z*sc + sh)
__global__ __launch_bounds__(256) void k_norm_relu(const float* __restrict__ z,
                                                   const float* __restrict__ stats,
                                                   const float* __restrict__ g,
                                                   const float* __restrict__ bnb,
                                                   float* __restrict__ h) {
    __shared__ float sc[32], sh[32];
    if (threadIdx.x < 32) {
        int cc = threadIdx.x;
        float mu = stats[cc] * (1.0f / NN);
        float var = stats[32 + cc] * (1.0f / NN) - mu * mu;
        float s = g[cc] * rsqrtf(var + 1e-5f);
        sc[cc] = s;
        sh[cc] = bnb[cc] - mu * s;
    }
    __syncthreads();
    int i = blockIdx.x * 256 + threadIdx.x;
    if (i >= NN * 8) return;
    int c = (i & 7) * 4;
    float4 v = *(const float4*)(z + (size_t)i * 4);
    float4 o;
    o.x = fmaxf(v.x * sc[c + 0] + sh[c + 0], 0.f);
    o.y = fmaxf(v.y * sc[c + 1] + sh[c + 1], 0.f);
    o.z = fmaxf(v.z * sc[c + 2] + sh[c + 2], 0.f);
    o.w = fmaxf(v.w * sc[c + 3] + sh[c + 3], 0.f);
    *(float4*)(h + (size_t)i * 4) = o;
}

// ---------------- pool: batch sorted — accumulate runs, flush per boundary
__global__ __launch_bounds__(256) void k_pool(const float* __restrict__ h,
                                              const int* __restrict__ batch,
                                              float* __restrict__ gsum,
                                              float* __restrict__ gcnt) {
    int gid = blockIdx.x * 256 + threadIdx.x;
    int nb = (gid >> 3) * 8;
    if (nb >= NN) return;
    int c = (gid & 7) * 4;
    bool lead = (gid & 7) == 0;
    float4 acc = make_float4(0.f, 0.f, 0.f, 0.f);
    float cnt = 0.f;
    int cur = batch[nb];
#pragma unroll
    for (int k = 0; k < 8; ++k) {
        int n = nb + k;
        if (n >= NN) break;
        int bg = batch[n];
        if (bg != cur) {
            float* o = gsum + (size_t)cur * 32 + c;
            fadd(o + 0, acc.x); fadd(o + 1, acc.y);
            fadd(o + 2, acc.z); fadd(o + 3, acc.w);
            if (lead) fadd(&gcnt[cur], cnt);
            acc = make_float4(0.f, 0.f, 0.f, 0.f);
            cnt = 0.f;
            cur = bg;
        }
        float4 v = *(const float4*)(h + (size_t)n * 32 + c);
        acc.x += v.x; acc.y += v.y; acc.z += v.z; acc.w += v.w;
        cnt += 1.f;
    }
    float* o = gsum + (size_t)cur * 32 + c;
    fadd(o + 0, acc.x); fadd(o + 1, acc.y);
    fadd(o + 2, acc.z); fadd(o + 3, acc.w);
    if (lead) fadd(&gcnt[cur], cnt);
}

__global__ __launch_bounds__(256) void k_head(const float* __restrict__ gsum,
                                              const float* __restrict__ gcnt,
                                              const float* __restrict__ l1w,
                                              const float* __restrict__ l1b,
                                              const float* __restrict__ l2w,
                                              const float* __restrict__ l2b,
                                              float* __restrict__ out) {
    __shared__ float s1[32 * 16], sb1[16], s2[16 * 2], sb2[2];
    for (int i = threadIdx.x; i < 512; i += 256) s1[i] = l1w[i];
    if (threadIdx.x < 16) sb1[threadIdx.x] = l1b[threadIdx.x];
    if (threadIdx.x < 32) s2[threadIdx.x] = l2w[threadIdx.x];
    if (threadIdx.x < 2) sb2[threadIdx.x] = l2b[threadIdx.x];
    __syncthreads();
    int gi = blockIdx.x * 256 + threadIdx.x;
    if (gi >= NG) return;
    float inv = 1.0f / fmaxf(gcnt[gi], 1.0f);
    float gm[32];
#pragma unroll
    for (int c = 0; c < 32; c += 4) {
        float4 v = *(const float4*)(gsum + (size_t)gi * 32 + c);
        gm[c + 0] = v.x * inv;
        gm[c + 1] = v.y * inv;
        gm[c + 2] = v.z * inv;
        gm[c + 3] = v.w * inv;
    }
    float a[16];
#pragma unroll
    for (int j = 0; j < 16; ++j) {
        float t = sb1[j];
#pragma unroll
        for (int c = 0; c < 32; ++c) t += gm[c] * s1[c * 16 + j];
        a[j] = fmaxf(t, 0.f);
    }
    float o0 = sb2[0], o1 = sb2[1];
#pragma unroll
    for (int j = 0; j < 16; ++j) {
        o0 += a[j] * s2[j * 2 + 0];
        o1 += a[j] * s2[j * 2 + 1];
    }
    out[gi * 2 + 0] = o0;
    out[gi * 2 + 1] = o1;
}

extern "C" void kernel_launch(void* const* d_in, const int* in_sizes, int n_in,
                              void* d_out, int out_size, void* d_ws, size_t ws_size,
                              hipStream_t stream) {
    const float* x = (const float*)d_in[0];
    const int* ei = (const int*)d_in[1];
    const float* ea = (const float*)d_in[2];
    const int* batch = (const int*)d_in[3];
    const float* node_w = (const float*)d_in[4];
    const float* node_b = (const float*)d_in[5];
    const float* edge_w = (const float*)d_in[6];
    const float* edge_b = (const float*)d_in[7];
    const float* w1 = (const float*)d_in[8];
    const float* b1 = (const float*)d_in[9];
    const float* w2 = (const float*)d_in[10];
    const float* b2 = (const float*)d_in[11];
    const float* bng = (const float*)d_in[12];
    const float* bnb = (const float*)d_in[13];
    const float* l1w = (const float*)d_in[14];
    const float* l1b = (const float*)d_in[15];
    const float* l2w = (const float*)d_in[16];
    const float* l2b = (const float*)d_in[17];
    float* out = (float*)d_out;

    // workspace layout (units: float/4B)
    float* h = (float*)d_ws;                       // NN*32 = 6.4M
    float* zb = h + (size_t)NN * 32;               // NN*32 (agg/z; aliased tmp recs)
    float* gsum = zb + (size_t)NN * 32;            // NG*32
    float* gcnt = gsum + (size_t)NG * 32;          // NG
    float* stats = gcnt + NG;                      // 64
    int* counts = (int*)(stats + 64);              // SCAN_PAD
    int* part = counts + SCAN_PAD;                 // 1024
    int* row_off = part + 1024;                    // NN+1
    int* recs2_base = row_off + NN + 1 + 2;        // NE*3 uints (12B recs)
    uint3* recs2 = (uint3*)recs2_base;
    uint3* tmp = (uint3*)zb;                       // NE*3 = 6.0M uints <= 6.4M floats

    size_t need_f = (size_t)NN * 64 + (size_t)NG * 33 + 64 + SCAN_PAD + 1024 +
                    ((size_t)NN + 3) + (size_t)NE * 3;
    bool use_fast = ws_size >= need_f * 4;

    if (use_fast) {
        // partition + sort FIRST (tmp aliases zb, free until first aggregate)
        k_hist<<<NPBLK, 256, 0, stream>>>(ei, counts);
        k_scanA<<<NSB1, 256, 0, stream>>>(counts, part);
        k_scanB<<<1, 1024, 0, stream>>>(part);
        k_scanC<<<NSB1, 256, 0, stream>>>(counts, part);
        k_part_scatter<<<NPBLK, 256, 0, stream>>>(ei, ea, counts, tmp);
        k_bucket_sort<<<NBKT, 256, 0, stream>>>(counts, tmp, recs2, row_off);
    }

    k_node_embed<<<(NN + 255) / 256, 256, 0, stream>>>(x, node_w, node_b, h);

    for (int l = 0; l < 2; ++l) {
        hipMemsetAsync(stats, 0, 64 * sizeof(float), stream);
        if (use_fast) {
            k_aggregate<<<(NN * 8 + 255) / 256, 256, 0, stream>>>(row_off, recs2,
                                                                  edge_w, edge_b, h, zb);
        } else {
            hipMemsetAsync(zb, 0, (size_t)NN * 32 * sizeof(float), stream);
            k_edge_scatter<<<(NE * 8) / 256, 256, 0, stream>>>(ei, ea, edge_w, edge_b, h, zb);
        }
        k_mlp_stats<<<(NN + 255) / 256, 256, 0, stream>>>(h, zb, w1 + l * 2400, b1 + l * 75,
                                                          w2 + l * 2400, b2 + l * 32, stats);
        k_norm_relu<<<(NN * 8 + 255) / 256, 256, 0, stream>>>(zb, stats, bng + l * 32,
                                                              bnb + l * 32, h);
    }

    hipMemsetAsync(gsum, 0, (size_t)(NG * 33) * sizeof(float), stream);
    k_pool<<<(NN + 255) / 256, 256, 0, stream>>>(h, batch, gsum, gcnt);
    k_head<<<(NG + 255) / 256, 256, 0, stream>>>(gsum, gcnt, l1w, l1b, l2w, l2b, out);
}